// Round 3
// baseline (161.877 us; speedup 1.0000x reference)
//
#include <hip/hip_runtime.h>
#include <stdint.h>

#define N_DET 8192
#define E_DIM 64
#define LSTR 132   // padded LDS k-row stride (words); 33 float4 per k-row

typedef float f4v __attribute__((ext_vector_type(4)));

__device__ __forceinline__ unsigned fmap(float x) {
    unsigned b = __float_as_uint(x);
    return (b & 0x80000000u) ? ~b : (b | 0x80000000u);
}
__device__ __forceinline__ unsigned long long umax64(unsigned long long a, unsigned long long b) {
    return a > b ? a : b;
}

// ---------------- K1: embed both detection sets ----------------
__global__ __launch_bounds__(256) void k_embed(
    const float* __restrict__ dt, const float* __restrict__ dt1,
    const float* __restrict__ W1, const float* __restrict__ b1,
    const float* __restrict__ W2, const float* __restrict__ b2,
    float* __restrict__ eout)
{
    int wave = (blockIdx.x * 256 + threadIdx.x) >> 6;
    int lane = threadIdx.x & 63;
    if (wave >= 2 * N_DET) return;
    const float* src = (wave < N_DET) ? (dt + (size_t)wave * 4)
                                      : (dt1 + (size_t)(wave - N_DET) * 4);
    float x0 = src[0], x1 = src[1], x2 = src[2], x3 = src[3];
    float h = b1[lane];
    h = fmaf(x0, W1[lane],        h);
    h = fmaf(x1, W1[64  + lane],  h);
    h = fmaf(x2, W1[128 + lane],  h);
    h = fmaf(x3, W1[192 + lane],  h);
    h = fmaxf(h, 0.0f);
    float e = b2[lane];
    #pragma unroll
    for (int k = 0; k < 64; ++k) {
        float hk = __shfl(h, k, 64);
        e = fmaf(hk, W2[k * 64 + lane], e);
    }
    float s = e * e;
    #pragma unroll
    for (int m = 32; m >= 1; m >>= 1) s += __shfl_xor(s, m, 64);
    float n = sqrtf(s);
    n = fmaxf(n, 1e-12f);
    eout[(size_t)wave * 64 + lane] = e / n;
}

// ---------------- K2: fused sim + per-row max/argmax ----------------
// Block: 128 rows x 256 cols (two 128-col tiles sharing the A stage).
// 256 threads, 8x8 outputs per thread per tile. LDS k-major, stride 132.
__global__ __launch_bounds__(256, 2) void k_sim_fused(
    const float* __restrict__ et, const float* __restrict__ et1,
    float* __restrict__ sim, unsigned long long* __restrict__ rowkey)
{
    __shared__ float As[64 * LSTR];
    __shared__ float Bs[64 * LSTR];
    const int tid = threadIdx.x;
    const int bx = blockIdx.x;          // 256-col supertile, 0..31
    const int by = blockIdx.y;          // 128-row tile, 0..63
    const int tx = tid & 15;
    const int ty = tid >> 4;

    // stage A (once per block): global row-major -> LDS k-major
    {
        const float4* ag = (const float4*)(et + (size_t)by * 128 * 64);
        #pragma unroll
        for (int i = 0; i < 8; ++i) {
            int f = tid + i * 256;
            int m = f >> 4;
            int k = (f & 15) * 4;
            float4 v = ag[f];
            As[(k + 0) * LSTR + m] = v.x;
            As[(k + 1) * LSTR + m] = v.y;
            As[(k + 2) * LSTR + m] = v.z;
            As[(k + 3) * LSTR + m] = v.w;
        }
    }
    // stage B tile 0
    {
        const float4* bg = (const float4*)(et1 + (size_t)bx * 256 * 64);
        #pragma unroll
        for (int i = 0; i < 8; ++i) {
            int f = tid + i * 256;
            int m = f >> 4;
            int k = (f & 15) * 4;
            float4 v = bg[f];
            Bs[(k + 0) * LSTR + m] = v.x;
            Bs[(k + 1) * LSTR + m] = v.y;
            Bs[(k + 2) * LSTR + m] = v.z;
            Bs[(k + 3) * LSTR + m] = v.w;
        }
    }
    __syncthreads();

    unsigned long long keys[8];
    #pragma unroll
    for (int i = 0; i < 8; ++i) keys[i] = 0ull;

    const f4v* As4 = (const f4v*)As;
    const f4v* Bs4 = (const f4v*)Bs;

    #pragma unroll 2
    for (int t = 0; t < 2; ++t) {
        float acc[8][8];
        #pragma unroll
        for (int i = 0; i < 8; ++i)
            #pragma unroll
            for (int j = 0; j < 8; ++j) acc[i][j] = 0.0f;

        #pragma unroll 8
        for (int k = 0; k < 64; ++k) {
            const int base = k * 33;
            f4v a0 = As4[base + ty];
            f4v a1 = As4[base + 16 + ty];
            f4v b0 = Bs4[base + tx];
            f4v b1 = Bs4[base + 16 + tx];
            float a[8] = {a0.x, a0.y, a0.z, a0.w, a1.x, a1.y, a1.z, a1.w};
            float b[8] = {b0.x, b0.y, b0.z, b0.w, b1.x, b1.y, b1.z, b1.w};
            #pragma unroll
            for (int i = 0; i < 8; ++i)
                #pragma unroll
                for (int j = 0; j < 8; ++j)
                    acc[i][j] = fmaf(a[i], b[j], acc[i][j]);
        }

        // restage B tile 1 behind a barrier (all waves done reading Bs),
        // overlapping the epilogue below with the staging-load latency.
        if (t == 0) {
            __syncthreads();
            const float4* bg = (const float4*)(et1 + ((size_t)bx * 256 + 128) * 64);
            #pragma unroll
            for (int i = 0; i < 8; ++i) {
                int f = tid + i * 256;
                int m = f >> 4;
                int k = (f & 15) * 4;
                float4 v = bg[f];
                Bs[(k + 0) * LSTR + m] = v.x;
                Bs[(k + 1) * LSTR + m] = v.y;
                Bs[(k + 2) * LSTR + m] = v.z;
                Bs[(k + 3) * LSTR + m] = v.w;
            }
        }

        // epilogue: nontemporal stores + in-register row max/argmax
        const int cbase = bx * 256 + t * 128;
        #pragma unroll
        for (int i = 0; i < 8; ++i) {
            int mrow = (i < 4) ? (ty * 4 + i) : (64 + ty * 4 + (i - 4));
            size_t rg = (size_t)by * 128 + mrow;
            f4v* sp = (f4v*)(sim + rg * N_DET + cbase);
            f4v v0 = {acc[i][0], acc[i][1], acc[i][2], acc[i][3]};
            f4v v1 = {acc[i][4], acc[i][5], acc[i][6], acc[i][7]};
            __builtin_nontemporal_store(v0, sp + tx);
            __builtin_nontemporal_store(v1, sp + 16 + tx);

            // strict > with ascending col order == first-occurrence argmax
            float bv = acc[i][0]; int bj = 0;
            #pragma unroll
            for (int j = 1; j < 8; ++j) {
                bool c = acc[i][j] > bv;
                bv = c ? acc[i][j] : bv;
                bj = c ? j : bj;
            }
            int col = cbase + ((bj < 4) ? (tx * 4 + bj) : (64 + tx * 4 + (bj - 4)));
            unsigned long long key =
                ((unsigned long long)fmap(bv) << 32) | (unsigned)(~col);
            keys[i] = umax64(keys[i], key);
        }

        if (t == 0) __syncthreads();   // B tile 1 staged before next k-loop
    }

    // one butterfly + one atomic per row (keys merged across both tiles)
    #pragma unroll
    for (int i = 0; i < 8; ++i) {
        unsigned long long key = keys[i];
        #pragma unroll
        for (int m = 1; m < 16; m <<= 1)
            key = umax64(key, __shfl_xor(key, m, 64));
        if (tx == 0) {
            int mrow = (i < 4) ? (ty * 4 + i) : (64 + ty * 4 + (i - 4));
            atomicMax(&rowkey[(size_t)by * 128 + mrow], key);
        }
    }
}

// ---------------- K0: zero rowkey+winner (contiguous 2*N u64) ----------------
__global__ void k_init(unsigned long long* __restrict__ p) {
    p[blockIdx.x * 256 + threadIdx.x] = 0ull;
}

// ---------------- K3/K4: greedy matching via per-column winner ----------------
__global__ void k_claim(const unsigned long long* __restrict__ rowkey,
                        unsigned long long* __restrict__ winner, unsigned uthr) {
    int i = blockIdx.x * 256 + threadIdx.x;
    if (i >= N_DET) return;
    unsigned long long k = rowkey[i];
    unsigned u = (unsigned)(k >> 32);
    if (u > uthr) {
        unsigned col = ~(unsigned)k;
        unsigned long long claim = ((unsigned long long)u << 32) | (~(unsigned)i);
        atomicMax(&winner[col], claim);
    }
}

__global__ void k_match(const unsigned long long* __restrict__ rowkey,
                        const unsigned long long* __restrict__ winner,
                        float* __restrict__ out, unsigned uthr) {
    int i = blockIdx.x * 256 + threadIdx.x;
    if (i >= N_DET) return;
    unsigned long long k = rowkey[i];
    unsigned u = (unsigned)(k >> 32);
    float m = -1.0f;
    if (u > uthr) {
        unsigned col = ~(unsigned)k;
        unsigned long long claim = ((unsigned long long)u << 32) | (~(unsigned)i);
        if (winner[col] == claim) m = (float)col;
    }
    out[i] = m;
}

extern "C" void kernel_launch(void* const* d_in, const int* in_sizes, int n_in,
                              void* d_out, int out_size, void* d_ws, size_t ws_size,
                              hipStream_t stream) {
    const float* dt  = (const float*)d_in[0];
    const float* dt1 = (const float*)d_in[1];
    const float* W1  = (const float*)d_in[2];
    const float* b1  = (const float*)d_in[3];
    const float* W2  = (const float*)d_in[4];
    const float* b2  = (const float*)d_in[5];

    float* out = (float*)d_out;            // [0:8192) matches (float), then sim row-major
    float* sim = out + N_DET;

    char* ws = (char*)d_ws;
    float* et  = (float*)ws;                                  // 8192*64 f32
    float* et1 = et + (size_t)N_DET * E_DIM;                  // 8192*64 f32
    unsigned long long* rowkey = (unsigned long long*)(ws + 2ull * N_DET * E_DIM * 4);
    unsigned long long* winner = rowkey + N_DET;              // contiguous after rowkey

    unsigned uthr;
    { union { float f; unsigned u; } c; c.f = 0.3f; uthr = c.u | 0x80000000u; }

    k_embed<<<(2 * N_DET) / 4, 256, 0, stream>>>(dt, dt1, W1, b1, W2, b2, et);
    k_init<<<(2 * N_DET) / 256, 256, 0, stream>>>(rowkey);    // zeros rowkey + winner

    dim3 g2(N_DET / 256, N_DET / 128);
    k_sim_fused<<<g2, 256, 0, stream>>>(et, et1, sim, rowkey);

    k_claim<<<N_DET / 256, 256, 0, stream>>>(rowkey, winner, uthr);
    k_match<<<N_DET / 256, 256, 0, stream>>>(rowkey, winner, out, uthr);
}